// Round 3
// baseline (420.061 us; speedup 1.0000x reference)
//
#include <hip/hip_runtime.h>
#include <stdint.h>

#define NB 2
#define SL 4096
#define NH 16
#define HD 128
#define DS 256
#define CK 256
#define NCH 16
#define NSQ 4
#define DI 2048

#define EPST 132   // epilogue LDS row stride (u16): 4-row offset = 8 banks -> conflict-free

typedef unsigned short u16;
typedef unsigned int u32;
typedef __attribute__((ext_vector_type(8))) __bf16 bf16x8;
typedef __attribute__((ext_vector_type(4))) float f32x4;

__device__ __forceinline__ int tor(int dir, int t) { return dir ? (SL - 1 - t) : t; }

__device__ __forceinline__ u16 f2bf(float f) {
  u32 u = __float_as_uint(f);
  u = u + 0x7fffu + ((u >> 16) & 1u);   // RNE
  return (u16)(u >> 16);
}
__device__ __forceinline__ float bf2f(u16 s) {
  return __uint_as_float(((u32)s) << 16);
}

__device__ __forceinline__ void gl_lds16(const u16* g, u16* l) {
  __builtin_amdgcn_global_load_lds((const __attribute__((address_space(1))) u32*)g,
                                   (__attribute__((address_space(3))) u32*)l, 16, 0, 0);
}

// Stage a 128x32 bf16 tile (row stride 256 elems in global) into LDS [128][32],
// 16B chunks XOR-swizzled by ((row>>1)&3). Wave w stages rows [w*32, w*32+32).
__device__ __forceinline__ void stage_tile(const u16* __restrict__ src, u16* lds,
                                           int lane, int w, int k0) {
  int sgrow = lane >> 2, sc = lane & 3;
  int r0 = w << 5;
  int ra = r0 + sgrow, rb = ra + 16;
  int kqa = (sc ^ ((ra >> 1) & 3)) << 3;
  int kqb = (sc ^ ((rb >> 1) & 3)) << 3;
  gl_lds16(src + (size_t)ra * 256 + k0 + kqa, lds + r0 * 32);
  gl_lds16(src + (size_t)rb * 256 + k0 + kqb, lds + (r0 + 16) * 32);
}

__device__ __forceinline__ bf16x8 frag(const u16* lds, int base_row, int m, int quad) {
  int row = base_row + m;
  return *(const bf16x8*)&lds[row * 32 + ((quad ^ ((row >> 1) & 3)) << 3)];
}

__device__ __forceinline__ void mfma16(const u16* As, const u16* Bs, int wi, int wp,
                                       int m, int quad, f32x4 acc[4][4]) {
  bf16x8 af[4], bv[4];
#pragma unroll
  for (int r = 0; r < 4; ++r) af[r] = frag(As, wi + (r << 4), m, quad);
#pragma unroll
  for (int c = 0; c < 4; ++c) bv[c] = frag(Bs, wp + (c << 4), m, quad);
#pragma unroll
  for (int r = 0; r < 4; ++r)
#pragma unroll
    for (int c = 0; c < 4; ++c)
      acc[r][c] = __builtin_amdgcn_mfma_f32_16x16x32_bf16(af[r], bv[c], acc[r][c], 0, 0, 0);
}

// ---- prep: softplus(dt), per-chunk cumsum of dA -----------------------------
__global__ __launch_bounds__(256) void kprep(const float* __restrict__ dt,
                                             const float* __restrict__ A_log,
                                             float* __restrict__ csb,
                                             float* __restrict__ dtvb,
                                             float* __restrict__ cdecb) {
  int blk = blockIdx.x;                 // sj*16 + h
  int h = blk & 15, sj = blk >> 4;
  int s = sj >> 4, j = sj & 15;
  int b = s & 1, dir = s >> 1;
  int i = threadIdx.x;
  int to = tor(dir, j * CK + i);
  __shared__ float sbuf[CK];
  float a = -expf(A_log[h]);
  float raw = dt[((size_t)(b * SL + to)) * (2 * NH) + dir * NH + h];
  float sp = (raw > 20.f) ? raw : log1pf(expf(raw));
  sbuf[i] = sp * a;
  __syncthreads();
  for (int off = 1; off < CK; off <<= 1) {
    float v = (i >= off) ? sbuf[i - off] : 0.f;
    __syncthreads();
    sbuf[i] += v;
    __syncthreads();
  }
  float csv = sbuf[i];
  size_t base = ((size_t)sj * NH + h) * CK;
  csb[base + i] = csv;
  dtvb[base + i] = sp;
  if (i == CK - 1) cdecb[sj * NH + h] = expf(csv);
}

// ---- cast BC -> bf16 B/C with flip applied: [s][t][n] ------------------------
__global__ __launch_bounds__(256) void kcast(const float* __restrict__ BC,
                                             u16* __restrict__ Bbf,
                                             u16* __restrict__ Cbf) {
  int blk = blockIdx.x;                 // s*SL + t
  int s = blk >> 12, t = blk & (SL - 1);
  int b = s & 1, dir = s >> 1;
  int tsrc = tor(dir, t);
  int tid = threadIdx.x;
  const float* src = BC + ((size_t)(b * SL + tsrc)) * (2 * DS);
  size_t dstb = ((size_t)s * SL + t) * DS;
  Bbf[dstb + tid] = f2bf(src[tid]);
  Cbf[dstb + tid] = f2bf(src[DS + tid]);
}

// ---- transpose B within chunk: BbfT[sj][n][k] --------------------------------
__global__ __launch_bounds__(256) void ktransB(const u16* __restrict__ Bbf,
                                               u16* __restrict__ BbfT) {
  int sj = blockIdx.x;
  int s = sj >> 4, j = sj & 15;
  __shared__ u16 T[64 * 264];
  int tid = threadIdx.x;
  const u16* src = Bbf + ((size_t)s * SL + j * CK) * DS;
  u16* dst = BbfT + (size_t)sj * DS * CK;
  int kr = tid >> 2, part = (tid & 3) * 64;
  for (int k0 = 0; k0 < CK; k0 += 64) {
    __syncthreads();
    {
      const uint4* gs = (const uint4*)(src + (size_t)(k0 + kr) * DS + part);
      uint4* tb = (uint4*)&T[kr * 264 + part];
#pragma unroll
      for (int q = 0; q < 8; ++q) tb[q] = gs[q];
    }
    __syncthreads();
    int n = tid;
    u16 col[64];
#pragma unroll
    for (int kq = 0; kq < 64; ++kq) col[kq] = T[kq * 264 + n];
    uint4* ds_ = (uint4*)(dst + (size_t)n * CK + k0);
#pragma unroll
    for (int q = 0; q < 8; ++q) {
      uint4 wv;
      wv.x = (u32)col[q * 8 + 0] | ((u32)col[q * 8 + 1] << 16);
      wv.y = (u32)col[q * 8 + 2] | ((u32)col[q * 8 + 3] << 16);
      wv.z = (u32)col[q * 8 + 4] | ((u32)col[q * 8 + 5] << 16);
      wv.w = (u32)col[q * 8 + 6] | ((u32)col[q * 8 + 7] << 16);
      ds_[q] = wv;
    }
  }
}

// ---- xsT[inst][p][k] = bf16( x[t(k)][h*128+p] * e^{-cs_k} * dt_k ) ----------
__global__ __launch_bounds__(256) void kxsT(const float* __restrict__ xg,
                                            const float* __restrict__ csb,
                                            const float* __restrict__ dtvb,
                                            u16* __restrict__ xsT) {
  int inst = blockIdx.x;                // ((s*16+j)*16+h)
  int h = inst & 15, sj = inst >> 4;
  int s = sj >> 4, j = sj & 15;
  int b = s & 1, dir = s >> 1;
  int tid = threadIdx.x;
  __shared__ u16 Ls[128 * 40];          // [p][kk], stride 40
  size_t cbase = ((size_t)sj * NH + h) * CK;
  u16* dst = xsT + (size_t)inst * (128 * 256);
  int kk = tid >> 3;
  int pg = (tid & 7) * 16;
  int p2 = tid >> 1, half = tid & 1;
  for (int k0 = 0; k0 < CK; k0 += 32) {
    int kglob = k0 + kk;
    float sc_ = expf(-csb[cbase + kglob]) * dtvb[cbase + kglob];
    int t = tor(dir, j * CK + kglob);
    const float* src = xg + ((size_t)(b * SL + t)) * DI + h * HD + pg;
    float4 v0 = ((const float4*)src)[0];
    float4 v1 = ((const float4*)src)[1];
    float4 v2 = ((const float4*)src)[2];
    float4 v3 = ((const float4*)src)[3];
    float vv[16] = {v0.x, v0.y, v0.z, v0.w, v1.x, v1.y, v1.z, v1.w,
                    v2.x, v2.y, v2.z, v2.w, v3.x, v3.y, v3.z, v3.w};
    __syncthreads();
#pragma unroll
    for (int q = 0; q < 16; ++q) Ls[(pg + q) * 40 + kk] = f2bf(vv[q] * sc_);
    __syncthreads();
    uint4 w0 = *(const uint4*)&Ls[p2 * 40 + half * 16];
    uint4 w1 = *(const uint4*)&Ls[p2 * 40 + half * 16 + 8];
    *(uint4*)&dst[(size_t)p2 * 256 + k0 + half * 16] = w0;
    *(uint4*)&dst[(size_t)p2 * 256 + k0 + half * 16 + 8] = w1;
  }
}

// ---- CBm[sj][i][k] = bf16( sum_n C[i,n]*B[k,n] ), masked k<=i ---------------
__global__ __launch_bounds__(256) void kcb(const u16* __restrict__ Cbf,
                                           const u16* __restrict__ Bbf,
                                           u16* __restrict__ CBm) {
  int blk = blockIdx.x;
  int tri = blk % 3;                    // 0:(0,0) 1:(1,0) 2:(1,1)
  int sj = blk / 3;
  int it0 = tri ? 128 : 0;
  int kt0 = (tri == 2) ? 128 : 0;
  int s = sj >> 4, j = sj & 15;
  __shared__ u16 smem[128 * EPST];
  u16* As = smem;
  u16* Bs = smem + 4096;
  int tid = threadIdx.x;
  int w = tid >> 6, lane = tid & 63;
  int wi = (w >> 1) << 6, wp = (w & 1) << 6;
  int m = lane & 15, quad = lane >> 4;
  const u16* Ab = Cbf + ((size_t)s * SL + j * CK + it0) * DS;
  const u16* Bb = Bbf + ((size_t)s * SL + j * CK + kt0) * DS;
  f32x4 zini = {0.f, 0.f, 0.f, 0.f};
  f32x4 acc[4][4];
#pragma unroll
  for (int r = 0; r < 4; ++r)
#pragma unroll
    for (int c = 0; c < 4; ++c) acc[r][c] = zini;
  for (int ks = 0; ks < 8; ++ks) {
    int k0 = ks << 5;
    stage_tile(Ab, As, lane, w, k0);
    stage_tile(Bb, Bs, lane, w, k0);
    __syncthreads();
    mfma16(As, Bs, wi, wp, m, quad, acc);
    __syncthreads();
  }
  int diag = (it0 == kt0);
#pragma unroll
  for (int r = 0; r < 4; ++r)
#pragma unroll
    for (int rg = 0; rg < 4; ++rg) {
      int irow = wi + (r << 4) + (quad << 2) + rg;
#pragma unroll
      for (int c = 0; c < 4; ++c) {
        int kcol = wp + (c << 4) + m;
        float v = acc[r][c][rg];
        if (diag && kcol > irow) v = 0.f;
        smem[irow * EPST + kcol] = f2bf(v);
      }
    }
  __syncthreads();
  {
    u16* dstb = CBm + ((size_t)sj * CK + it0) * CK + kt0;
    int rr = tid >> 1, off = (tid & 1) << 6;
    const uint4* srcv = (const uint4*)&smem[rr * EPST + off];
    uint4* dstv = (uint4*)(dstb + (size_t)rr * CK + off);
#pragma unroll
    for (int q = 0; q < 8; ++q) dstv[q] = srcv[q];
  }
}

// ---- states: prevT[inst][p][n] = e^{cs_last} * sum_k xs[p,k]*B[n,k] ----------
__global__ __launch_bounds__(256) void kstates(const u16* __restrict__ xsT,
                                               const u16* __restrict__ BbfT,
                                               const float* __restrict__ cdecb,
                                               u16* __restrict__ prevT) {
  int blk = blockIdx.x;
  int ntile = blk & 1;
  int inst = blk >> 1;
  int h = inst & 15, sj = inst >> 4;
  int nt0 = ntile << 7;
  __shared__ u16 smem[128 * EPST];
  u16* As = smem;
  u16* Bs = smem + 4096;
  int tid = threadIdx.x;
  int w = tid >> 6, lane = tid & 63;
  int wi = (w >> 1) << 6, wp = (w & 1) << 6;
  int m = lane & 15, quad = lane >> 4;
  const u16* Ab = xsT + (size_t)inst * (128 * 256);        // rows p
  const u16* Bb = BbfT + ((size_t)sj * DS + nt0) * CK;     // rows n
  f32x4 zini = {0.f, 0.f, 0.f, 0.f};
  f32x4 acc[4][4];
#pragma unroll
  for (int r = 0; r < 4; ++r)
#pragma unroll
    for (int c = 0; c < 4; ++c) acc[r][c] = zini;
  for (int ks = 0; ks < 8; ++ks) {
    int k0 = ks << 5;
    stage_tile(Ab, As, lane, w, k0);
    stage_tile(Bb, Bs, lane, w, k0);
    __syncthreads();
    mfma16(As, Bs, wi, wp, m, quad, acc);
    __syncthreads();
  }
  float scale = cdecb[sj * NH + h];
#pragma unroll
  for (int r = 0; r < 4; ++r)
#pragma unroll
    for (int rg = 0; rg < 4; ++rg) {
      int prow = wi + (r << 4) + (quad << 2) + rg;
#pragma unroll
      for (int c = 0; c < 4; ++c) {
        int ncol = wp + (c << 4) + m;
        smem[prow * EPST + ncol] = f2bf(acc[r][c][rg] * scale);
      }
    }
  __syncthreads();
  {
    u16* dstb = prevT + (size_t)inst * (128 * 256) + nt0;
    int rr = tid >> 1, off = (tid & 1) << 6;
    const uint4* srcv = (const uint4*)&smem[rr * EPST + off];
    uint4* dstv = (uint4*)(dstb + (size_t)rr * 256 + off);
#pragma unroll
    for (int q = 0; q < 8; ++q) dstv[q] = srcv[q];
  }
}

// ---- inter-chunk recurrence over prevT[s][j][h][p][n], 8 states per thread ---
__global__ __launch_bounds__(256) void kscan(u16* __restrict__ prevT,
                                             const float* __restrict__ cdecb) {
  int g = blockIdx.x * 256 + threadIdx.x;
  int n0 = (g & 31) * 8;
  int p = (g >> 5) & 127;
  int h = (g >> 12) & 15;
  int s = g >> 16;
  size_t base = ((size_t)(s * 256 + h) * 128 + p) * 256 + n0;
  const size_t stride = (size_t)NH * 128 * 256;
  float carry[8] = {0.f, 0.f, 0.f, 0.f, 0.f, 0.f, 0.f, 0.f};
  for (int j = 0; j < NCH; ++j) {
    size_t idx = base + (size_t)j * stride;
    uint4 u = *(const uint4*)&prevT[idx];
    u32 uu[4] = {u.x, u.y, u.z, u.w};
    float sv[8];
#pragma unroll
    for (int q = 0; q < 4; ++q) {
      sv[2 * q] = __uint_as_float(uu[q] << 16);
      sv[2 * q + 1] = __uint_as_float(uu[q] & 0xffff0000u);
    }
    uint4 wv;
    wv.x = (u32)f2bf(carry[0]) | ((u32)f2bf(carry[1]) << 16);
    wv.y = (u32)f2bf(carry[2]) | ((u32)f2bf(carry[3]) << 16);
    wv.z = (u32)f2bf(carry[4]) | ((u32)f2bf(carry[5]) << 16);
    wv.w = (u32)f2bf(carry[6]) | ((u32)f2bf(carry[7]) << 16);
    *(uint4*)&prevT[idx] = wv;
    float d = cdecb[(s * NCH + j) * NH + h];
#pragma unroll
    for (int q = 0; q < 8; ++q) carry[q] = carry[q] * d + sv[q];
  }
}

// ---- y[i,p] = e^{cs_i} * ( CBm(i,:)·xs(:,p) + C(i,:)·prev(:,p) ) -------------
__global__ __launch_bounds__(256) void ky(const u16* __restrict__ CBm,
                                          const u16* __restrict__ Cbf,
                                          const u16* __restrict__ xsT,
                                          const u16* __restrict__ prevT,
                                          const float* __restrict__ csb,
                                          u16* __restrict__ ytmpb) {
  int blk = blockIdx.x;
  int itile = blk & 1;
  int inst = blk >> 1;
  int h = inst & 15, sj = inst >> 4;
  int s = sj >> 4, j = sj & 15;
  int it0 = itile << 7;
  __shared__ u16 smem[128 * EPST];
  u16* As = smem;
  u16* Bs = smem + 4096;
  int tid = threadIdx.x;
  int w = tid >> 6, lane = tid & 63;
  int wi = (w >> 1) << 6, wp = (w & 1) << 6;
  int m = lane & 15, quad = lane >> 4;

  const u16* Ai = CBm + ((size_t)sj * CK + it0) * CK;
  const u16* Ae = Cbf + ((size_t)s * SL + j * CK + it0) * DS;
  const u16* Bi = xsT + (size_t)inst * (128 * 256);
  const u16* Be = prevT + (size_t)inst * (128 * 256);

  int nIntra = itile ? 8 : 4;           // upper-zero CB tiles skipped for itile 0
  int nTot = nIntra + 8;

  f32x4 zini = {0.f, 0.f, 0.f, 0.f};
  f32x4 acc[4][4];
#pragma unroll
  for (int r = 0; r < 4; ++r)
#pragma unroll
    for (int c = 0; c < 4; ++c) acc[r][c] = zini;

  for (int ks = 0; ks < nTot; ++ks) {
    int intra = ks < nIntra;
    int k0 = (intra ? ks : ks - nIntra) << 5;
    const u16* Ab = intra ? Ai : Ae;
    const u16* Bb = intra ? Bi : Be;
    stage_tile(Ab, As, lane, w, k0);
    stage_tile(Bb, Bs, lane, w, k0);
    __syncthreads();
    mfma16(As, Bs, wi, wp, m, quad, acc);
    __syncthreads();
  }
  const float* csrow = csb + ((size_t)sj * NH + h) * CK + it0;
#pragma unroll
  for (int r = 0; r < 4; ++r)
#pragma unroll
    for (int rg = 0; rg < 4; ++rg) {
      int irow = wi + (r << 4) + (quad << 2) + rg;
      float esc = expf(csrow[irow]);
#pragma unroll
      for (int c = 0; c < 4; ++c) {
        int pcol = wp + (c << 4) + m;
        smem[irow * EPST + pcol] = f2bf(acc[r][c][rg] * esc);
      }
    }
  __syncthreads();
  {
    u16* yb = ytmpb + ((size_t)s * SL + j * CK + it0) * DI + h * HD;
    int rr = tid >> 1, off = (tid & 1) << 6;
    const uint4* srcv = (const uint4*)&smem[rr * EPST + off];
    uint4* dstv = (uint4*)(yb + (size_t)rr * DI + off);
#pragma unroll
    for (int q = 0; q < 8; ++q) dstv[q] = srcv[q];
  }
}

// ---- WT[d][h] = W[h][d] ------------------------------------------------------
__global__ __launch_bounds__(256) void kwt(const float* __restrict__ Wg,
                                           float* __restrict__ WT) {
  int g = blockIdx.x * 256 + threadIdx.x;   // 32768
  int d = g >> 4, h = g & 15;
  WT[g] = Wg[(size_t)h * DI + d];
}

// ---- gate[row][h] = sum_d x[row][d]*WT[d][h] + D[h]; 8 rows per wave ---------
__global__ __launch_bounds__(256) void kgate(const float* __restrict__ xg,
                                             const float* __restrict__ WT,
                                             const float* __restrict__ Dg,
                                             float* __restrict__ gate) {
  int wave = (blockIdx.x * 256 + threadIdx.x) >> 6;  // 1024 waves, 8 rows each
  int lane = threadIdx.x & 63;
  int gg = lane >> 4, h = lane & 15;
  int row0 = wave * 8;
  const float* xb = xg + (size_t)row0 * DI;
  float acc[8] = {0.f, 0.f, 0.f, 0.f, 0.f, 0.f, 0.f, 0.f};
  for (int q = 0; q < 128; ++q) {
    int d = gg * 4 + 16 * q;
    float w0 = WT[(d + 0) * 16 + h];
    float w1 = WT[(d + 1) * 16 + h];
    float w2 = WT[(d + 2) * 16 + h];
    float w3 = WT[(d + 3) * 16 + h];
#pragma unroll
    for (int r = 0; r < 8; ++r) {
      float4 xv = *(const float4*)&xb[(size_t)r * DI + d];
      acc[r] += xv.x * w0 + xv.y * w1 + xv.z * w2 + xv.w * w3;
    }
  }
#pragma unroll
  for (int r = 0; r < 8; ++r) {
    acc[r] += __shfl_down(acc[r], 32);
    acc[r] += __shfl_down(acc[r], 16);
  }
  if (lane < 16) {
    float dv = Dg[h];
#pragma unroll
    for (int r = 0; r < 8; ++r) gate[(size_t)(row0 + r) * NH + h] = acc[r] + dv;
  }
}

// ---- combine: out[t] = y_fw[t-1] + y_bw[SL-2-t] + x[t]*gate ------------------
__device__ __forceinline__ void unpk8(uint4 u, float* o) {
  o[0] = __uint_as_float(u.x << 16); o[1] = __uint_as_float(u.x & 0xffff0000u);
  o[2] = __uint_as_float(u.y << 16); o[3] = __uint_as_float(u.y & 0xffff0000u);
  o[4] = __uint_as_float(u.z << 16); o[5] = __uint_as_float(u.z & 0xffff0000u);
  o[6] = __uint_as_float(u.w << 16); o[7] = __uint_as_float(u.w & 0xffff0000u);
}

__global__ __launch_bounds__(256) void kcombine(const float* __restrict__ xg,
                                                const float* __restrict__ gate,
                                                const u16* __restrict__ ytmpb,
                                                float* __restrict__ out) {
  int bid = blockIdx.x;
  int b = bid >> 12;
  int t = bid & (SL - 1);
  int tid = threadIdx.x;
  int d0 = tid * 8;
  float g = gate[(size_t)(b * SL + t) * NH + (tid >> 4)];
  float fy[8] = {0.f, 0.f, 0.f, 0.f, 0.f, 0.f, 0.f, 0.f};
  float by[8] = {0.f, 0.f, 0.f, 0.f, 0.f, 0.f, 0.f, 0.f};
  if (t > 0) {
    uint4 u = *(const uint4*)(ytmpb + ((size_t)(b * SL + (t - 1))) * DI + d0);
    unpk8(u, fy);
  }
  if (t < SL - 1) {
    uint4 u = *(const uint4*)(ytmpb + ((size_t)((2 + b) * SL + (SL - 2 - t))) * DI + d0);
    unpk8(u, by);
  }
  const float* xr = xg + ((size_t)(b * SL + t)) * DI + d0;
  float4 x0 = ((const float4*)xr)[0];
  float4 x1 = ((const float4*)xr)[1];
  float xa[8] = {x0.x, x0.y, x0.z, x0.w, x1.x, x1.y, x1.z, x1.w};
  float* op = out + ((size_t)(b * SL + t)) * DI + d0;
  float4 o0, o1;
  o0.x = fy[0] + by[0] + xa[0] * g; o0.y = fy[1] + by[1] + xa[1] * g;
  o0.z = fy[2] + by[2] + xa[2] * g; o0.w = fy[3] + by[3] + xa[3] * g;
  o1.x = fy[4] + by[4] + xa[4] * g; o1.y = fy[5] + by[5] + xa[5] * g;
  o1.z = fy[6] + by[6] + xa[6] * g; o1.w = fy[7] + by[7] + xa[7] * g;
  ((float4*)op)[0] = o0;
  ((float4*)op)[1] = o1;
}

extern "C" void kernel_launch(void* const* d_in, const int* in_sizes, int n_in,
                              void* d_out, int out_size, void* d_ws, size_t ws_size,
                              hipStream_t stream) {
  (void)in_sizes; (void)n_in; (void)out_size; (void)ws_size;
  const float* x     = (const float*)d_in[0];
  const float* BC    = (const float*)d_in[1];
  const float* dt    = (const float*)d_in[2];
  const float* A_log = (const float*)d_in[3];
  const float* Dg    = (const float*)d_in[4];
  const float* W     = (const float*)d_in[5];
  float* out = (float*)d_out;

  char* p = (char*)d_ws;
  float* cs   = (float*)p;  p += (size_t)NSQ * NCH * NH * CK * 4;        // 1 MB
  float* dtv  = (float*)p;  p += (size_t)NSQ * NCH * NH * CK * 4;        // 1 MB
  float* cdec = (float*)p;  p += (size_t)NSQ * NCH * NH * 4;             // 4 KB
  float* WT   = (float*)p;  p += (size_t)DI * NH * 4;                    // 128 KB
  float* gateb= (float*)p;  p += (size_t)NB * SL * NH * 4;               // 512 KB
  u16* Bbf    = (u16*)p;    p += (size_t)NSQ * SL * DS * 2;              // 8.4 MB
  u16* Cbf    = (u16*)p;    p += (size_t)NSQ * SL * DS * 2;              // 8.4 MB
  u16* BbfT   = (u16*)p;    p += (size_t)NSQ * NCH * DS * CK * 2;        // 8.4 MB
  u16* CBm    = (u16*)p;    p += (size_t)NSQ * NCH * CK * CK * 2;        // 8.4 MB
  u16* xsT    = (u16*)p;    p += (size_t)NSQ * NCH * NH * HD * CK * 2;   // 67 MB
  u16* prevT  = (u16*)p;    p += (size_t)NSQ * NCH * NH * HD * DS * 2;   // 67 MB
  u16* ytmpb  = (u16*)p;    p += (size_t)NSQ * SL * DI * 2;              // 67 MB

  hipLaunchKernelGGL(kprep,   dim3(NSQ * NCH * NH),      dim3(CK),  0, stream, dt, A_log, cs, dtv, cdec);
  hipLaunchKernelGGL(kcast,   dim3(NSQ * SL),            dim3(256), 0, stream, BC, Bbf, Cbf);
  hipLaunchKernelGGL(ktransB, dim3(NSQ * NCH),           dim3(256), 0, stream, Bbf, BbfT);
  hipLaunchKernelGGL(kxsT,    dim3(NSQ * NCH * NH),      dim3(256), 0, stream, x, cs, dtv, xsT);
  hipLaunchKernelGGL(kcb,     dim3(NSQ * NCH * 3),       dim3(256), 0, stream, Cbf, Bbf, CBm);
  hipLaunchKernelGGL(kwt,     dim3(DI * NH / 256),       dim3(256), 0, stream, W, WT);
  hipLaunchKernelGGL(kgate,   dim3(NB * SL / 32),        dim3(256), 0, stream, x, WT, Dg, gateb);
  hipLaunchKernelGGL(kstates, dim3(NSQ * NCH * NH * 2),  dim3(256), 0, stream, xsT, BbfT, cdec, prevT);
  hipLaunchKernelGGL(kscan,   dim3(NSQ * NH * HD * DS / (256 * 8)), dim3(256), 0, stream, prevT, cdec);
  hipLaunchKernelGGL(ky,      dim3(NSQ * NCH * NH * 2),  dim3(256), 0, stream, CBm, Cbf, xsT, prevT, cs, ytmpb);
  hipLaunchKernelGGL(kcombine,dim3(NB * SL),             dim3(256), 0, stream, x, gateb, ytmpb, out);
}

// Round 5
// 418.603 us; speedup vs baseline: 1.0035x; 1.0035x over previous
//
#include <hip/hip_runtime.h>
#include <stdint.h>

#define NB 2
#define SL 4096
#define NH 16
#define HD 128
#define DS 256
#define CK 256
#define NCH 16
#define NSQ 4
#define DI 2048

#define EPST 132   // epilogue LDS row stride (u16): conflict-free repack

typedef unsigned short u16;
typedef unsigned int u32;
typedef __attribute__((ext_vector_type(8))) __bf16 bf16x8;
typedef __attribute__((ext_vector_type(4))) float f32x4;

__device__ __forceinline__ int tor(int dir, int t) { return dir ? (SL - 1 - t) : t; }

__device__ __forceinline__ u16 f2bf(float f) {
  u32 u = __float_as_uint(f);
  u = u + 0x7fffu + ((u >> 16) & 1u);   // RNE
  return (u16)(u >> 16);
}
__device__ __forceinline__ float bf2f(u16 s) {
  return __uint_as_float(((u32)s) << 16);
}

// ---- register-staged tile (128x32 bf16, global row stride 256) ---------------
// thread t handles row = t>>1, chunks q0,q0+1 where q0 = (t&1)*2 (16B chunks).
struct Stg { uint4 a, b; };

__device__ __forceinline__ Stg ld_tile(const u16* __restrict__ src, int row, int q0, int k0) {
  const uint4* p = (const uint4*)(src + (size_t)row * 256 + k0 + (q0 << 3));
  Stg s; s.a = p[0]; s.b = p[1]; return s;
}
// LDS layout [row][32] with 16B-chunk XOR swizzle by ((row>>1)&3)
__device__ __forceinline__ void st_tile(u16* buf, int row, int q0, Stg s) {
  int sw = (row >> 1) & 3;
  *(uint4*)&buf[row * 32 + ((q0 ^ sw) << 3)] = s.a;
  *(uint4*)&buf[row * 32 + (((q0 + 1) ^ sw) << 3)] = s.b;
}

__device__ __forceinline__ bf16x8 frag(const u16* lds, int base_row, int m, int quad) {
  int row = base_row + m;
  return *(const bf16x8*)&lds[row * 32 + ((quad ^ ((row >> 1) & 3)) << 3)];
}

__device__ __forceinline__ void mfma16(const u16* As, const u16* Bs, int wi, int wp,
                                       int m, int quad, f32x4 acc[4][4]) {
  bf16x8 af[4], bv[4];
#pragma unroll
  for (int r = 0; r < 4; ++r) af[r] = frag(As, wi + (r << 4), m, quad);
#pragma unroll
  for (int c = 0; c < 4; ++c) bv[c] = frag(Bs, wp + (c << 4), m, quad);
#pragma unroll
  for (int r = 0; r < 4; ++r)
#pragma unroll
    for (int c = 0; c < 4; ++c)
      acc[r][c] = __builtin_amdgcn_mfma_f32_16x16x32_bf16(af[r], bv[c], acc[r][c], 0, 0, 0);
}

// ---- prep: softplus(dt), per-chunk cumsum of dA -----------------------------
__global__ __launch_bounds__(256) void kprep(const float* __restrict__ dt,
                                             const float* __restrict__ A_log,
                                             float* __restrict__ csb,
                                             float* __restrict__ dtvb,
                                             float* __restrict__ cdecb) {
  int blk = blockIdx.x;                 // sj*16 + h
  int h = blk & 15, sj = blk >> 4;
  int s = sj >> 4, j = sj & 15;
  int b = s & 1, dir = s >> 1;
  int i = threadIdx.x;
  int to = tor(dir, j * CK + i);
  __shared__ float sbuf[CK];
  float a = -expf(A_log[h]);
  float raw = dt[((size_t)(b * SL + to)) * (2 * NH) + dir * NH + h];
  float sp = (raw > 20.f) ? raw : log1pf(expf(raw));
  sbuf[i] = sp * a;
  __syncthreads();
  for (int off = 1; off < CK; off <<= 1) {
    float v = (i >= off) ? sbuf[i - off] : 0.f;
    __syncthreads();
    sbuf[i] += v;
    __syncthreads();
  }
  float csv = sbuf[i];
  size_t base = ((size_t)sj * NH + h) * CK;
  csb[base + i] = csv;
  dtvb[base + i] = sp;
  if (i == CK - 1) cdecb[sj * NH + h] = expf(csv);
}

// ---- cast BC -> bf16 B/C with flip applied: [s][t][n] ------------------------
__global__ __launch_bounds__(256) void kcast(const float* __restrict__ BC,
                                             u16* __restrict__ Bbf,
                                             u16* __restrict__ Cbf) {
  int blk = blockIdx.x;                 // s*SL + t
  int s = blk >> 12, t = blk & (SL - 1);
  int b = s & 1, dir = s >> 1;
  int tsrc = tor(dir, t);
  int tid = threadIdx.x;
  const float* src = BC + ((size_t)(b * SL + tsrc)) * (2 * DS);
  size_t dstb = ((size_t)s * SL + t) * DS;
  Bbf[dstb + tid] = f2bf(src[tid]);
  Cbf[dstb + tid] = f2bf(src[DS + tid]);
}

// ---- transpose B within chunk: BbfT[sj][n][k] --------------------------------
__global__ __launch_bounds__(256) void ktransB(const u16* __restrict__ Bbf,
                                               u16* __restrict__ BbfT) {
  int sj = blockIdx.x;
  int s = sj >> 4, j = sj & 15;
  __shared__ u16 T[64 * 264];
  int tid = threadIdx.x;
  const u16* src = Bbf + ((size_t)s * SL + j * CK) * DS;
  u16* dst = BbfT + (size_t)sj * DS * CK;
  int kr = tid >> 2, part = (tid & 3) * 64;
  for (int k0 = 0; k0 < CK; k0 += 64) {
    __syncthreads();
    {
      const uint4* gs = (const uint4*)(src + (size_t)(k0 + kr) * DS + part);
      uint4* tb = (uint4*)&T[kr * 264 + part];
#pragma unroll
      for (int q = 0; q < 8; ++q) tb[q] = gs[q];
    }
    __syncthreads();
    int n = tid;
    u16 col[64];
#pragma unroll
    for (int kq = 0; kq < 64; ++kq) col[kq] = T[kq * 264 + n];
    uint4* ds_ = (uint4*)(dst + (size_t)n * CK + k0);
#pragma unroll
    for (int q = 0; q < 8; ++q) {
      uint4 wv;
      wv.x = (u32)col[q * 8 + 0] | ((u32)col[q * 8 + 1] << 16);
      wv.y = (u32)col[q * 8 + 2] | ((u32)col[q * 8 + 3] << 16);
      wv.z = (u32)col[q * 8 + 4] | ((u32)col[q * 8 + 5] << 16);
      wv.w = (u32)col[q * 8 + 6] | ((u32)col[q * 8 + 7] << 16);
      ds_[q] = wv;
    }
  }
}

// ---- xsT[inst][p][k] = bf16( x[t(k)][h*128+p] * e^{-cs_k} * dt_k ) ----------
__global__ __launch_bounds__(256) void kxsT(const float* __restrict__ xg,
                                            const float* __restrict__ csb,
                                            const float* __restrict__ dtvb,
                                            u16* __restrict__ xsT) {
  int inst = blockIdx.x;                // ((s*16+j)*16+h)
  int h = inst & 15, sj = inst >> 4;
  int s = sj >> 4, j = sj & 15;
  int b = s & 1, dir = s >> 1;
  int tid = threadIdx.x;
  __shared__ u16 Ls[128 * 40];          // [p][kk], stride 40
  size_t cbase = ((size_t)sj * NH + h) * CK;
  u16* dst = xsT + (size_t)inst * (128 * 256);
  int kk = tid >> 3;
  int pg = (tid & 7) * 16;
  int p2 = tid >> 1, half = tid & 1;
  float4 v[4];
  {
    int t = tor(dir, j * CK + kk);
    const float* src = xg + ((size_t)(b * SL + t)) * DI + h * HD + pg;
    v[0] = ((const float4*)src)[0]; v[1] = ((const float4*)src)[1];
    v[2] = ((const float4*)src)[2]; v[3] = ((const float4*)src)[3];
  }
  for (int k0 = 0; k0 < CK; k0 += 32) {
    int kglob = k0 + kk;
    float sc_ = expf(-csb[cbase + kglob]) * dtvb[cbase + kglob];
    float vv[16] = {v[0].x, v[0].y, v[0].z, v[0].w, v[1].x, v[1].y, v[1].z, v[1].w,
                    v[2].x, v[2].y, v[2].z, v[2].w, v[3].x, v[3].y, v[3].z, v[3].w};
    __syncthreads();
#pragma unroll
    for (int q = 0; q < 16; ++q) Ls[(pg + q) * 40 + kk] = f2bf(vv[q] * sc_);
    // prefetch next k-block while LDS readback below proceeds
    if (k0 + 32 < CK) {
      int t = tor(dir, j * CK + k0 + 32 + kk);
      const float* src = xg + ((size_t)(b * SL + t)) * DI + h * HD + pg;
      v[0] = ((const float4*)src)[0]; v[1] = ((const float4*)src)[1];
      v[2] = ((const float4*)src)[2]; v[3] = ((const float4*)src)[3];
    }
    __syncthreads();
    uint4 w0 = *(const uint4*)&Ls[p2 * 40 + half * 16];
    uint4 w1 = *(const uint4*)&Ls[p2 * 40 + half * 16 + 8];
    *(uint4*)&dst[(size_t)p2 * 256 + k0 + half * 16] = w0;
    *(uint4*)&dst[(size_t)p2 * 256 + k0 + half * 16 + 8] = w1;
  }
}

// ---- CBm[sj][i][k] = bf16( sum_n C[i,n]*B[k,n] ), masked k<=i ---------------
__global__ __launch_bounds__(256) void kcb(const u16* __restrict__ Cbf,
                                           const u16* __restrict__ Bbf,
                                           u16* __restrict__ CBm) {
  int blk = blockIdx.x;
  int tri = blk % 3;                    // 0:(0,0) 1:(1,0) 2:(1,1)
  int sj = blk / 3;
  int it0 = tri ? 128 : 0;
  int kt0 = (tri == 2) ? 128 : 0;
  int s = sj >> 4, j = sj & 15;
  __shared__ u16 smem[128 * EPST];
  int tid = threadIdx.x;
  int w = tid >> 6, lane = tid & 63;
  int wi = (w >> 1) << 6, wp = (w & 1) << 6;
  int m = lane & 15, quad = lane >> 4;
  int row = tid >> 1, q0 = (tid & 1) << 1;
  const u16* Ab = Cbf + ((size_t)s * SL + j * CK + it0) * DS;
  const u16* Bb = Bbf + ((size_t)s * SL + j * CK + kt0) * DS;
  f32x4 zini = {0.f, 0.f, 0.f, 0.f};
  f32x4 acc[4][4];
#pragma unroll
  for (int r = 0; r < 4; ++r)
#pragma unroll
    for (int c = 0; c < 4; ++c) acc[r][c] = zini;
  const int n = 8;
  Stg pa = ld_tile(Ab, row, q0, 0);
  Stg pb = ld_tile(Bb, row, q0, 0);
  st_tile(smem, row, q0, pa);
  st_tile(smem + 8192, row, q0, pb);
  pa = ld_tile(Ab, row, q0, 32);
  pb = ld_tile(Bb, row, q0, 32);
  for (int ks = 1; ks < n; ++ks) {
    __syncthreads();
    int cur = (ks & 1) << 12;
    st_tile(smem + cur, row, q0, pa);
    st_tile(smem + 8192 + cur, row, q0, pb);
    if (ks + 1 < n) {
      pa = ld_tile(Ab, row, q0, (ks + 1) << 5);
      pb = ld_tile(Bb, row, q0, (ks + 1) << 5);
    }
    int prv = ((ks - 1) & 1) << 12;
    mfma16(smem + prv, smem + 8192 + prv, wi, wp, m, quad, acc);
  }
  __syncthreads();
  {
    int prv = ((n - 1) & 1) << 12;
    mfma16(smem + prv, smem + 8192 + prv, wi, wp, m, quad, acc);
  }
  __syncthreads();
  int diag = (it0 == kt0);
#pragma unroll
  for (int r = 0; r < 4; ++r)
#pragma unroll
    for (int rg = 0; rg < 4; ++rg) {
      int irow = wi + (r << 4) + (quad << 2) + rg;
#pragma unroll
      for (int c = 0; c < 4; ++c) {
        int kcol = wp + (c << 4) + m;
        float v = acc[r][c][rg];
        if (diag && kcol > irow) v = 0.f;
        smem[irow * EPST + kcol] = f2bf(v);
      }
    }
  __syncthreads();
  {
    u16* dstb = CBm + ((size_t)sj * CK + it0) * CK + kt0;
    int rr = tid >> 1, off = (tid & 1) << 6;
    const uint4* srcv = (const uint4*)&smem[rr * EPST + off];
    uint4* dstv = (uint4*)(dstb + (size_t)rr * CK + off);
#pragma unroll
    for (int q = 0; q < 8; ++q) dstv[q] = srcv[q];
  }
}

// ---- states: prevT[inst][p][n] = e^{cs_last} * sum_k xs[p,k]*B[n,k] ----------
__global__ __launch_bounds__(256) void kstates(const u16* __restrict__ xsT,
                                               const u16* __restrict__ BbfT,
                                               const float* __restrict__ cdecb,
                                               u16* __restrict__ prevT) {
  int blk = blockIdx.x;
  int ntile = blk & 1;
  int inst = blk >> 1;
  int h = inst & 15, sj = inst >> 4;
  int nt0 = ntile << 7;
  __shared__ u16 smem[128 * EPST];
  int tid = threadIdx.x;
  int w = tid >> 6, lane = tid & 63;
  int wi = (w >> 1) << 6, wp = (w & 1) << 6;
  int m = lane & 15, quad = lane >> 4;
  int row = tid >> 1, q0 = (tid & 1) << 1;
  const u16* Ab = xsT + (size_t)inst * (128 * 256);        // rows p
  const u16* Bb = BbfT + ((size_t)sj * DS + nt0) * CK;     // rows n
  f32x4 zini = {0.f, 0.f, 0.f, 0.f};
  f32x4 acc[4][4];
#pragma unroll
  for (int r = 0; r < 4; ++r)
#pragma unroll
    for (int c = 0; c < 4; ++c) acc[r][c] = zini;
  const int n = 8;
  Stg pa = ld_tile(Ab, row, q0, 0);
  Stg pb = ld_tile(Bb, row, q0, 0);
  st_tile(smem, row, q0, pa);
  st_tile(smem + 8192, row, q0, pb);
  pa = ld_tile(Ab, row, q0, 32);
  pb = ld_tile(Bb, row, q0, 32);
  for (int ks = 1; ks < n; ++ks) {
    __syncthreads();
    int cur = (ks & 1) << 12;
    st_tile(smem + cur, row, q0, pa);
    st_tile(smem + 8192 + cur, row, q0, pb);
    if (ks + 1 < n) {
      pa = ld_tile(Ab, row, q0, (ks + 1) << 5);
      pb = ld_tile(Bb, row, q0, (ks + 1) << 5);
    }
    int prv = ((ks - 1) & 1) << 12;
    mfma16(smem + prv, smem + 8192 + prv, wi, wp, m, quad, acc);
  }
  __syncthreads();
  {
    int prv = ((n - 1) & 1) << 12;
    mfma16(smem + prv, smem + 8192 + prv, wi, wp, m, quad, acc);
  }
  __syncthreads();
  float scale = cdecb[sj * NH + h];
#pragma unroll
  for (int r = 0; r < 4; ++r)
#pragma unroll
    for (int rg = 0; rg < 4; ++rg) {
      int prow = wi + (r << 4) + (quad << 2) + rg;
#pragma unroll
      for (int c = 0; c < 4; ++c) {
        int ncol = wp + (c << 4) + m;
        smem[prow * EPST + ncol] = f2bf(acc[r][c][rg] * scale);
      }
    }
  __syncthreads();
  {
    u16* dstb = prevT + (size_t)inst * (128 * 256) + nt0;
    int rr = tid >> 1, off = (tid & 1) << 6;
    const uint4* srcv = (const uint4*)&smem[rr * EPST + off];
    uint4* dstv = (uint4*)(dstb + (size_t)rr * 256 + off);
#pragma unroll
    for (int q = 0; q < 8; ++q) dstv[q] = srcv[q];
  }
}

// ---- inter-chunk recurrence over prevT[s][j][h][p][n], 8 states per thread ---
__global__ __launch_bounds__(256) void kscan(u16* __restrict__ prevT,
                                             const float* __restrict__ cdecb) {
  int g = blockIdx.x * 256 + threadIdx.x;
  int n0 = (g & 31) * 8;
  int p = (g >> 5) & 127;
  int h = (g >> 12) & 15;
  int s = g >> 16;
  size_t base = ((size_t)(s * 256 + h) * 128 + p) * 256 + n0;
  const size_t stride = (size_t)NH * 128 * 256;
  float carry[8] = {0.f, 0.f, 0.f, 0.f, 0.f, 0.f, 0.f, 0.f};
  uint4 u = *(const uint4*)&prevT[base];
  for (int j = 0; j < NCH; ++j) {
    size_t idx = base + (size_t)j * stride;
    uint4 un;
    if (j + 1 < NCH) un = *(const uint4*)&prevT[idx + stride];
    u32 uu[4] = {u.x, u.y, u.z, u.w};
    float sv[8];
#pragma unroll
    for (int q = 0; q < 4; ++q) {
      sv[2 * q] = __uint_as_float(uu[q] << 16);
      sv[2 * q + 1] = __uint_as_float(uu[q] & 0xffff0000u);
    }
    uint4 wv;
    wv.x = (u32)f2bf(carry[0]) | ((u32)f2bf(carry[1]) << 16);
    wv.y = (u32)f2bf(carry[2]) | ((u32)f2bf(carry[3]) << 16);
    wv.z = (u32)f2bf(carry[4]) | ((u32)f2bf(carry[5]) << 16);
    wv.w = (u32)f2bf(carry[6]) | ((u32)f2bf(carry[7]) << 16);
    *(uint4*)&prevT[idx] = wv;
    float d = cdecb[(s * NCH + j) * NH + h];
#pragma unroll
    for (int q = 0; q < 8; ++q) carry[q] = carry[q] * d + sv[q];
    u = un;
  }
}

// ---- y[i,p] = e^{cs_i} * ( CBm(i,:)·xs(:,p) + C(i,:)·prev(:,p) ) -------------
__global__ __launch_bounds__(256) void ky(const u16* __restrict__ CBm,
                                          const u16* __restrict__ Cbf,
                                          const u16* __restrict__ xsT,
                                          const u16* __restrict__ prevT,
                                          const float* __restrict__ csb,
                                          u16* __restrict__ ytmpb) {
  int blk = blockIdx.x;
  int itile = blk & 1;
  int inst = blk >> 1;
  int h = inst & 15, sj = inst >> 4;
  int s = sj >> 4, j = sj & 15;
  int it0 = itile << 7;
  __shared__ u16 smem[128 * EPST];
  int tid = threadIdx.x;
  int w = tid >> 6, lane = tid & 63;
  int wi = (w >> 1) << 6, wp = (w & 1) << 6;
  int m = lane & 15, quad = lane >> 4;
  int row = tid >> 1, q0 = (tid & 1) << 1;

  const u16* Ai = CBm + ((size_t)sj * CK + it0) * CK;
  const u16* Ae = Cbf + ((size_t)s * SL + j * CK + it0) * DS;
  const u16* Bi = xsT + (size_t)inst * (128 * 256);
  const u16* Be = prevT + (size_t)inst * (128 * 256);

  int nIntra = itile ? 8 : 4;           // upper-zero CB tiles skipped for itile 0
  int n = nIntra + 8;

  f32x4 zini = {0.f, 0.f, 0.f, 0.f};
  f32x4 acc[4][4];
#pragma unroll
  for (int r = 0; r < 4; ++r)
#pragma unroll
    for (int c = 0; c < 4; ++c) acc[r][c] = zini;

#define KY_SRC(ks, Ap, Bp, kk)                                  \
  {                                                             \
    int intra_ = (ks) < nIntra;                                 \
    kk = (intra_ ? (ks) : (ks) - nIntra) << 5;                  \
    Ap = intra_ ? Ai : Ae;                                      \
    Bp = intra_ ? Bi : Be;                                      \
  }

  const u16 *Ap, *Bp; int kk;
  KY_SRC(0, Ap, Bp, kk);
  Stg pa = ld_tile(Ap, row, q0, kk);
  Stg pb = ld_tile(Bp, row, q0, kk);
  st_tile(smem, row, q0, pa);
  st_tile(smem + 8192, row, q0, pb);
  KY_SRC(1, Ap, Bp, kk);
  pa = ld_tile(Ap, row, q0, kk);
  pb = ld_tile(Bp, row, q0, kk);
  for (int ks = 1; ks < n; ++ks) {
    __syncthreads();
    int cur = (ks & 1) << 12;
    st_tile(smem + cur, row, q0, pa);
    st_tile(smem + 8192 + cur, row, q0, pb);
    if (ks + 1 < n) {
      KY_SRC(ks + 1, Ap, Bp, kk);
      pa = ld_tile(Ap, row, q0, kk);
      pb = ld_tile(Bp, row, q0, kk);
    }
    int prv = ((ks - 1) & 1) << 12;
    mfma16(smem + prv, smem + 8192 + prv, wi, wp, m, quad, acc);
  }
  __syncthreads();
  {
    int prv = ((n - 1) & 1) << 12;
    mfma16(smem + prv, smem + 8192 + prv, wi, wp, m, quad, acc);
  }
  __syncthreads();
#undef KY_SRC

  const float* csrow = csb + ((size_t)sj * NH + h) * CK + it0;
#pragma unroll
  for (int r = 0; r < 4; ++r)
#pragma unroll
    for (int rg = 0; rg < 4; ++rg) {
      int irow = wi + (r << 4) + (quad << 2) + rg;
      float esc = expf(csrow[irow]);
#pragma unroll
      for (int c = 0; c < 4; ++c) {
        int pcol = wp + (c << 4) + m;
        smem[irow * EPST + pcol] = f2bf(acc[r][c][rg] * esc);
      }
    }
  __syncthreads();
  {
    u16* yb = ytmpb + ((size_t)s * SL + j * CK + it0) * DI + h * HD;
    int rr = tid >> 1, off = (tid & 1) << 6;
    const uint4* srcv = (const uint4*)&smem[rr * EPST + off];
    uint4* dstv = (uint4*)(yb + (size_t)rr * DI + off);
#pragma unroll
    for (int q = 0; q < 8; ++q) dstv[q] = srcv[q];
  }
}

// ---- WT[d][h] = W[h][d] ------------------------------------------------------
__global__ __launch_bounds__(256) void kwt(const float* __restrict__ Wg,
                                           float* __restrict__ WT) {
  int g = blockIdx.x * 256 + threadIdx.x;   // 32768
  int d = g >> 4, h = g & 15;
  WT[g] = Wg[(size_t)h * DI + d];
}

// ---- gate[row][h] = sum_d x[row][d]*WT[d][h] + D[h]; 8 rows per wave ---------
__global__ __launch_bounds__(256) void kgate(const float* __restrict__ xg,
                                             const float* __restrict__ WT,
                                             const float* __restrict__ Dg,
                                             float* __restrict__ gate) {
  int wave = (blockIdx.x * 256 + threadIdx.x) >> 6;  // 1024 waves, 8 rows each
  int lane = threadIdx.x & 63;
  int gg = lane >> 4, h = lane & 15;
  int row0 = wave * 8;
  const float* xb = xg + (size_t)row0 * DI;
  float acc[8] = {0.f, 0.f, 0.f, 0.f, 0.f, 0.f, 0.f, 0.f};
  for (int q = 0; q < 128; ++q) {
    int d = gg * 4 + 16 * q;
    float w0 = WT[(d + 0) * 16 + h];
    float w1 = WT[(d + 1) * 16 + h];
    float w2 = WT[(d + 2) * 16 + h];
    float w3 = WT[(d + 3) * 16 + h];
#pragma unroll
    for (int r = 0; r < 8; ++r) {
      float4 xv = *(const float4*)&xb[(size_t)r * DI + d];
      acc[r] += xv.x * w0 + xv.y * w1 + xv.z * w2 + xv.w * w3;
    }
  }
#pragma unroll
  for (int r = 0; r < 8; ++r) {
    acc[r] += __shfl_down(acc[r], 32);
    acc[r] += __shfl_down(acc[r], 16);
  }
  if (lane < 16) {
    float dv = Dg[h];
#pragma unroll
    for (int r = 0; r < 8; ++r) gate[(size_t)(row0 + r) * NH + h] = acc[r] + dv;
  }
}

// ---- combine: out[t] = y_fw[t-1] + y_bw[SL-2-t] + x[t]*gate ------------------
__device__ __forceinline__ void unpk8(uint4 u, float* o) {
  o[0] = __uint_as_float(u.x << 16); o[1] = __uint_as_float(u.x & 0xffff0000u);
  o[2] = __uint_as_float(u.y << 16); o[3] = __uint_as_float(u.y & 0xffff0000u);
  o[4] = __uint_as_float(u.z << 16); o[5] = __uint_as_float(u.z & 0xffff0000u);
  o[6] = __uint_as_float(u.w << 16); o[7] = __uint_as_float(u.w & 0xffff0000u);
}

__global__ __launch_bounds__(256) void kcombine(const float* __restrict__ xg,
                                                const float* __restrict__ gate,
                                                const u16* __restrict__ ytmpb,
                                                float* __restrict__ out) {
  int bid = blockIdx.x;
  int b = bid >> 12;
  int t = bid & (SL - 1);
  int tid = threadIdx.x;
  int d0 = tid * 8;
  float g = gate[(size_t)(b * SL + t) * NH + (tid >> 4)];
  float fy[8] = {0.f, 0.f, 0.f, 0.f, 0.f, 0.f, 0.f, 0.f};
  float by[8] = {0.f, 0.f, 0.f, 0.f, 0.f, 0.f, 0.f, 0.f};
  if (t > 0) {
    uint4 u = *(const uint4*)(ytmpb + ((size_t)(b * SL + (t - 1))) * DI + d0);
    unpk8(u, fy);
  }
  if (t < SL - 1) {
    uint4 u = *(const uint4*)(ytmpb + ((size_t)((2 + b) * SL + (SL - 2 - t))) * DI + d0);
    unpk8(u, by);
  }
  const float* xr = xg + ((size_t)(b * SL + t)) * DI + d0;
  float4 x0 = ((const float4*)xr)[0];
  float4 x1 = ((const float4*)xr)[1];
  float xa[8] = {x0.x, x0.y, x0.z, x0.w, x1.x, x1.y, x1.z, x1.w};
  float* op = out + ((size_t)(b * SL + t)) * DI + d0;
  float4 o0, o1;
  o0.x = fy[0] + by[0] + xa[0] * g; o0.y = fy[1] + by[1] + xa[1] * g;
  o0.z = fy[2] + by[2] + xa[2] * g; o0.w = fy[3] + by[3] + xa[3] * g;
  o1.x = fy[4] + by[4] + xa[4] * g; o1.y = fy[5] + by[5] + xa[5] * g;
  o1.z = fy[6] + by[6] + xa[6] * g; o1.w = fy[7] + by[7] + xa[7] * g;
  ((float4*)op)[0] = o0;
  ((float4*)op)[1] = o1;
}

extern "C" void kernel_launch(void* const* d_in, const int* in_sizes, int n_in,
                              void* d_out, int out_size, void* d_ws, size_t ws_size,
                              hipStream_t stream) {
  (void)in_sizes; (void)n_in; (void)out_size; (void)ws_size;
  const float* x     = (const float*)d_in[0];
  const float* BC    = (const float*)d_in[1];
  const float* dt    = (const float*)d_in[2];
  const float* A_log = (const float*)d_in[3];
  const float* Dg    = (const float*)d_in[4];
  const float* W     = (const float*)d_in[5];
  float* out = (float*)d_out;

  char* p = (char*)d_ws;
  float* cs   = (float*)p;  p += (size_t)NSQ * NCH * NH * CK * 4;        // 1 MB
  float* dtv  = (float*)p;  p += (size_t)NSQ * NCH * NH * CK * 4;        // 1 MB
  float* cdec = (float*)p;  p += (size_t)NSQ * NCH * NH * 4;             // 4 KB
  float* WT   = (float*)p;  p += (size_t)DI * NH * 4;                    // 128 KB
  float* gateb= (float*)p;  p += (size_t)NB * SL * NH * 4;               // 512 KB
  u16* Bbf    = (u16*)p;    p += (size_t)NSQ * SL * DS * 2;              // 8.4 MB
  u16* Cbf    = (u16*)p;    p += (size_t)NSQ * SL * DS * 2;              // 8.4 MB
  u16* BbfT   = (u16*)p;    p += (size_t)NSQ * NCH * DS * CK * 2;        // 8.4 MB
  u16* CBm    = (u16*)p;    p += (size_t)NSQ * NCH * CK * CK * 2;        // 8.4 MB
  u16* xsT    = (u16*)p;    p += (size_t)NSQ * NCH * NH * HD * CK * 2;   // 67 MB
  u16* prevT  = (u16*)p;    p += (size_t)NSQ * NCH * NH * HD * DS * 2;   // 67 MB
  u16* ytmpb  = (u16*)p;    p += (size_t)NSQ * SL * DI * 2;              // 67 MB

  hipLaunchKernelGGL(kprep,   dim3(NSQ * NCH * NH),      dim3(CK),  0, stream, dt, A_log, cs, dtv, cdec);
  hipLaunchKernelGGL(kcast,   dim3(NSQ * SL),            dim3(256), 0, stream, BC, Bbf, Cbf);
  hipLaunchKernelGGL(ktransB, dim3(NSQ * NCH),           dim3(256), 0, stream, Bbf, BbfT);
  hipLaunchKernelGGL(kxsT,    dim3(NSQ * NCH * NH),      dim3(256), 0, stream, x, cs, dtv, xsT);
  hipLaunchKernelGGL(kcb,     dim3(NSQ * NCH * 3),       dim3(256), 0, stream, Cbf, Bbf, CBm);
  hipLaunchKernelGGL(kwt,     dim3(DI * NH / 256),       dim3(256), 0, stream, W, WT);
  hipLaunchKernelGGL(kgate,   dim3(NB * SL / 32),        dim3(256), 0, stream, x, WT, Dg, gateb);
  hipLaunchKernelGGL(kstates, dim3(NSQ * NCH * NH * 2),  dim3(256), 0, stream, xsT, BbfT, cdec, prevT);
  hipLaunchKernelGGL(kscan,   dim3(NSQ * NH * HD * DS / (256 * 8)), dim3(256), 0, stream, prevT, cdec);
  hipLaunchKernelGGL(ky,      dim3(NSQ * NCH * NH * 2),  dim3(256), 0, stream, CBm, Cbf, xsT, prevT, cs, ytmpb);
  hipLaunchKernelGGL(kcombine,dim3(NB * SL),             dim3(256), 0, stream, x, gateb, ytmpb, out);
}